// Round 8
// baseline (152.266 us; speedup 1.0000x reference)
//
#include <hip/hip_runtime.h>
#include <math.h>

// Problem constants (match reference)
constexpr int   B       = 2048;
constexpr int   P       = 4;
constexpr int   D       = 256;       // K of the GEMM
constexpr int   NNEG    = 32768;
constexpr int   NTILES  = NNEG / 64; // per-row exp2-sum partials (64-col patches)
constexpr float TEMP    = 0.05f;
constexpr float ALPHA   = 0.1f;
constexpr float EPS     = 1e-12f;
constexpr float INV_T   = 1.0f / TEMP;
// A-side rows are pre-scaled by (1/T)*log2(e) so the MFMA accumulator is
// directly q = sim/T * log2(e), and exp(sim/T) = exp2(q).  |q| <= ~30 so no
// max-tracking is needed (exp2 stays in fp32 range).
constexpr float SCALE_Q = 28.853900817779268f;

typedef __bf16 bf16x8 __attribute__((ext_vector_type(8)));
typedef float  f32x4  __attribute__((ext_vector_type(4)));

// fp32 -> bf16 (RNE), bit-level
__device__ inline unsigned short f2bf(float f) {
  unsigned int u = __float_as_uint(f);
  u = (u + 0x7fffu + ((u >> 16) & 1u)) >> 16;
  return (unsigned short)u;
}

// ---------------------------------------------------------------------------
// FRAGMENT-MAJOR layout: element (row, k) of a [R x 256] bf16 matrix lives at
//   p*4096 + c*512 + q*128 + r*8 + j        (ushort index)
// where p=row>>4, r=row&15, c=k>>5, q=(k>>3)&3, j=k&7.
// A (panel p, chunk c) fragment is 1024 contiguous bytes; MFMA lane l=r+16q
// reads its 16 B at byte offset l*16 -> one perfectly-coalesced
// global_load_dwordx4 per fragment, and global_load_lds staging of a fragment
// is exactly lane-contiguous (dest = base + lane*16).
// k is identically permuted for A and B, so the dot product is unchanged.
// ---------------------------------------------------------------------------

// ---------------------------------------------------------------------------
// Kernel 1 (fused prep): one wave per work row.
//   rows [0, B)         : normalize anchor, scale SCALE_Q, cast bf16 -> frag-major
//   rows [B, B+NNEG)    : normalize negative, cast bf16 -> frag-major
//   rows [B+NNEG,+B*P)  : pos_sim pair dot (exact fp32)
// ---------------------------------------------------------------------------
__global__ void prep_kernel(const float* __restrict__ a,
                            const float* __restrict__ pzx,
                            const float* __restrict__ n,
                            unsigned short* __restrict__ a_bf,
                            unsigned short* __restrict__ n_bf,
                            float* __restrict__ pos_sim,
                            float* __restrict__ loss_acc,
                            unsigned int* __restrict__ ticket) {
  if (blockIdx.x == 0 && threadIdx.x == 0) { *loss_acc = 0.0f; *ticket = 0u; }
  int w    = (blockIdx.x * blockDim.x + threadIdx.x) >> 6;
  int lane = threadIdx.x & 63;
  if (w < B + NNEG) {
    const float* src; unsigned short* dstm; int row; float post;
    if (w < B) { src = a + (size_t)w * D;       dstm = a_bf; row = w;     post = SCALE_Q; }
    else       { src = n + (size_t)(w - B) * D; dstm = n_bf; row = w - B; post = 1.0f; }
    float4 v = ((const float4*)src)[lane];
    float ss = v.x * v.x + v.y * v.y + v.z * v.z + v.w * v.w;
#pragma unroll
    for (int off = 32; off > 0; off >>= 1) ss += __shfl_xor(ss, off, 64);
    float inv = post / fmaxf(sqrtf(ss), EPS);
    ushort4 o;
    o.x = f2bf(v.x * inv); o.y = f2bf(v.y * inv);
    o.z = f2bf(v.z * inv); o.w = f2bf(v.w * inv);
    const int p = row >> 4, r = row & 15;
    const int c = lane >> 3, q = (lane >> 1) & 3, j0 = (lane & 1) * 4;
    *(ushort4*)(dstm + (size_t)p * 4096 + c * 512 + q * 128 + r * 8 + j0) = o;
  } else {
    int pw = w - (B + NNEG);           // 0..B*P-1
    if (pw >= B * P) return;
    int b = pw >> 2;                   // P == 4
    float4 av = ((const float4*)(a + (size_t)b * D))[lane];
    float4 pv = ((const float4*)(pzx + (size_t)pw * D))[lane];
    float d  = av.x * pv.x + av.y * pv.y + av.z * pv.z + av.w * pv.w;
    float sa = av.x * av.x + av.y * av.y + av.z * av.z + av.w * av.w;
    float sp = pv.x * pv.x + pv.y * pv.y + pv.z * pv.z + pv.w * pv.w;
#pragma unroll
    for (int off = 32; off > 0; off >>= 1) {
      d  += __shfl_xor(d, off, 64);
      sa += __shfl_xor(sa, off, 64);
      sp += __shfl_xor(sp, off, 64);
    }
    if (lane == 0) {
      float inva = 1.0f / fmaxf(sqrtf(sa), EPS);
      float invp = 1.0f / fmaxf(sqrtf(sp), EPS);
      pos_sim[pw] = d * inva * invp * INV_T;
    }
  }
}

// ---------------------------------------------------------------------------
// Kernel 2: bf16 MFMA GEMM fused with exp2-sum partials.
//
// STAGE-ONCE A-TILE: the block's full-K A-tile (128 rows x 256 k = 64
// fragments = 64 KB) is staged into LDS via global_load_lds ONCE, followed by
// the kernel's ONLY barrier.  The K-loop then has zero barriers (no recurring
// vmcnt(0)-drain, the structural stall of rounds 3/4) — A-frags come from LDS
// (ds_read_b128, lane-contiguous = conflict-free), B-frags come ping-pong
// direct from frag-major global (round-7 proven).  This removes the 4x
// per-block fragment-read redundancy on A and halves total L2 traffic
// (1 GB -> ~512 MB issued, B duplicates L1-absorbed), pushing the kernel from
// L2-bound (25% MfmaUtil) toward the 16.6 us MFMA floor.
//
// 128x128 tile, 4 waves (2x2), each wave 64x64 = 4x4 mfma_f32_16x16x32_bf16.
// XCD swizzle: block id&7 -> xcd owns a 32-ntile strip (2 MB of N) + all of
// A (1 MB) < 4 MB per-XCD L2.
//
// Epilogue: acc holds q = sim/T*log2e (A pre-scaled); per row, sum exp2(q)
// over the wave's 64 cols via 16-lane shuffle reduce -> part_s.
// ---------------------------------------------------------------------------
constexpr int BM = 128, BN = 128;

__global__ __launch_bounds__(256, 4) void negsim_mfma_kernel(
    const unsigned short* __restrict__ Af,   // frag-major [B][256]
    const unsigned short* __restrict__ Nf,   // frag-major [NNEG][256]
    float* __restrict__ part_s) {            // [B][NTILES]
  // 64 fragments x 512 ushorts = 64 KB, frag f = c*8 + p at offset f*512
  __shared__ __align__(16) unsigned short As[64 * 512];

  const int tid  = threadIdx.x;
  const int wave = tid >> 6;
  const int lane = tid & 63;
  const int wx   = wave & 1;   // N direction
  const int wy   = wave >> 1;  // M direction

  // XCD-aware decode of flat block id
  const int id   = blockIdx.x;
  const int xcd  = id & 7;
  const int j    = id >> 3;              // 0..511
  const int nblk = xcd * 32 + (j & 31);  // 0..255
  const int mblk = j >> 5;               // 0..15
  const int m0   = mblk * BM;
  const int n0   = nblk * BN;

  // ---- stage A-tile (64 frags) once: wave stages frags [wave*16, +16) ----
#pragma unroll
  for (int t = 0; t < 16; t++) {
    const int f = wave * 16 + t;       // 0..63
    const int c = f >> 3, p = f & 7;
    __builtin_amdgcn_global_load_lds(
        (const __attribute__((address_space(1))) unsigned int*)
            (Af + (size_t)((m0 >> 4) + p) * 4096 + c * 512 + lane * 8),
        (__attribute__((address_space(3))) unsigned int*)(As + f * 512 + lane * 8),
        16, 0, 0);
  }
  __syncthreads();   // the kernel's only barrier (drains the staging loads)

  // ---- K-loop: A from LDS, B ping-pong from global ----
  const unsigned short* Bp = Nf + (size_t)((n0 >> 4) + wx * 4) * 4096 + lane * 8;

  f32x4 acc[4][4] = {};
  bf16x8 b0[4], b1[4];

#pragma unroll
  for (int ni = 0; ni < 4; ni++)
    b0[ni] = *(const bf16x8*)(Bp + (size_t)ni * 4096);

#pragma unroll
  for (int c = 0; c < 8; c += 2) {
    // prefetch chunk c+1 (always exists: c is even, c+1 <= 7)
#pragma unroll
    for (int ni = 0; ni < 4; ni++)
      b1[ni] = *(const bf16x8*)(Bp + (size_t)ni * 4096 + (c + 1) * 512);
    {
      bf16x8 af[4];
#pragma unroll
      for (int mi = 0; mi < 4; mi++)
        af[mi] = *(const bf16x8*)&As[(c * 8 + wy * 4 + mi) * 512 + lane * 8];
#pragma unroll
      for (int mi = 0; mi < 4; mi++)
#pragma unroll
        for (int ni = 0; ni < 4; ni++)
          acc[mi][ni] = __builtin_amdgcn_mfma_f32_16x16x32_bf16(
              af[mi], b0[ni], acc[mi][ni], 0, 0, 0);
    }
    if (c + 2 < 8) {
#pragma unroll
      for (int ni = 0; ni < 4; ni++)
        b0[ni] = *(const bf16x8*)(Bp + (size_t)ni * 4096 + (c + 2) * 512);
    }
    {
      bf16x8 af[4];
#pragma unroll
      for (int mi = 0; mi < 4; mi++)
        af[mi] = *(const bf16x8*)&As[((c + 1) * 8 + wy * 4 + mi) * 512 + lane * 8];
#pragma unroll
      for (int mi = 0; mi < 4; mi++)
#pragma unroll
        for (int ni = 0; ni < 4; ni++)
          acc[mi][ni] = __builtin_amdgcn_mfma_f32_16x16x32_bf16(
              af[mi], b1[ni], acc[mi][ni], 0, 0, 0);
    }
  }

  // Epilogue: C/D layout row = mi*16 + (lane>>4)*4 + rr, col = ni*16+(lane&15).
#pragma unroll
  for (int mi = 0; mi < 4; mi++) {
#pragma unroll
    for (int rr = 0; rr < 4; rr++) {
      float s = __builtin_amdgcn_exp2f(acc[mi][0][rr]) +
                __builtin_amdgcn_exp2f(acc[mi][1][rr]) +
                __builtin_amdgcn_exp2f(acc[mi][2][rr]) +
                __builtin_amdgcn_exp2f(acc[mi][3][rr]);
#pragma unroll
      for (int off = 1; off < 16; off <<= 1) s += __shfl_xor(s, off, 64);
      if ((lane & 15) == 0) {
        int row = m0 + wy * 64 + mi * 16 + (lane >> 4) * 4 + rr;
        part_s[(size_t)row * NTILES + (nblk * 2 + wx)] = s;
      }
    }
  }
}

// ---------------------------------------------------------------------------
// Kernel 3: per-anchor loss + final reduce.  128 blocks x 256 threads; each
// 16-lane group handles one anchor (16-way split of the 512-partial sum).
// One atomicAdd per block (128 total) + ticket; last block writes out[0].
// ---------------------------------------------------------------------------
__global__ void loss_kernel(const float* __restrict__ part_s,
                            const float* __restrict__ pos_sim,
                            const int* __restrict__ counts,
                            float* __restrict__ loss_acc,
                            unsigned int* __restrict__ ticket,
                            float* __restrict__ out) {
  const int tid = threadIdx.x;
  const int b   = blockIdx.x * 16 + (tid >> 4);
  const int sub = tid & 15;
  const float* ps = part_s + (size_t)b * NTILES;
  float s = 0.0f;
#pragma unroll
  for (int i = 0; i < NTILES / 16; i++) s += ps[sub + i * 16];
  s += __shfl_xor(s, 1, 64);
  s += __shfl_xor(s, 2, 64);
  s += __shfl_xor(s, 4, 64);
  s += __shfl_xor(s, 8, 64);   // 16-lane group now holds full S

  float acc = 0.0f;
  if (sub == 0) {
    float L = logf(s);  // neg_lse in natural-log units
    float p0 = pos_sim[b * P + 0], p1 = pos_sim[b * P + 1];
    float p2 = pos_sim[b * P + 2], p3 = pos_sim[b * P + 3];
    int cnt = counts[b];
    float pj[P] = {p0, p1, p2, p3};
#pragma unroll
    for (int jj = 0; jj < P; jj++) {
      if (jj < cnt) {
        float hi = fmaxf(pj[jj], L), lo = fminf(pj[jj], L);
        acc += hi + log1pf(__expf(lo - hi)) - pj[jj];
      }
    }
    float mp = fmaxf(fmaxf(p0, p1), fmaxf(p2, p3));
    float e0 = __expf(p0 - mp), e1 = __expf(p1 - mp);
    float e2 = __expf(p2 - mp), e3 = __expf(p3 - mp);
    float se = e0 + e1 + e2 + e3;
    float wps = (e0 * p0 + e1 * p1 + e2 * p2 + e3 * p3) / se;
    if (cnt > 1) {
      float hi = fmaxf(wps, L), lo = fminf(wps, L);
      acc += ALPHA * (hi + log1pf(__expf(lo - hi)) - wps);
    }
  }
  // block reduce (only sub==0 lanes carry nonzero)
#pragma unroll
  for (int off = 32; off > 0; off >>= 1) acc += __shfl_xor(acc, off, 64);
  __shared__ float sa[4];
  int wid = tid >> 6, lane = tid & 63;
  if (lane == 0) sa[wid] = acc;
  __syncthreads();
  if (tid == 0) {
    atomicAdd(loss_acc, sa[0] + sa[1] + sa[2] + sa[3]);
    __threadfence();
    unsigned int t = atomicAdd(ticket, 1u);
    if (t == (unsigned int)gridDim.x - 1u) {
      float total = atomicAdd(loss_acc, 0.0f);  // atomic read-back
      out[0] = total / (float)B;
    }
  }
}

// ---------------------------------------------------------------------------
extern "C" void kernel_launch(void* const* d_in, const int* in_sizes, int n_in,
                              void* d_out, int out_size, void* d_ws,
                              size_t ws_size, hipStream_t stream) {
  const float* anc    = (const float*)d_in[0];
  const float* pos    = (const float*)d_in[1];
  const float* neg    = (const float*)d_in[2];
  const int*   counts = (const int*)d_in[3];
  float* out = (float*)d_out;

  // Workspace layout: ~21.1 MB
  unsigned short* a_bf = (unsigned short*)d_ws;          // B*D      (1 MB)
  unsigned short* n_bf = a_bf + (size_t)B * D;           // NNEG*D   (16 MB)
  float* part_s  = (float*)(n_bf + (size_t)NNEG * D);    // B*NTILES (4 MB)
  float* pos_sim = part_s + (size_t)B * NTILES;          // B*P
  float* loss_acc = pos_sim + B * P;                     // 1
  unsigned int* ticket = (unsigned int*)(loss_acc + 1);  // 1

  // 43008 work-rows (norm-cast B+NNEG, possim B*P), 4 waves/block
  prep_kernel<<<(B + NNEG + B * P) / 4, 256, 0, stream>>>(
      anc, pos, neg, a_bf, n_bf, pos_sim, loss_acc, ticket);

  negsim_mfma_kernel<<<4096, 256, 0, stream>>>(a_bf, n_bf, part_s);

  loss_kernel<<<B / 16, 256, 0, stream>>>(part_s, pos_sim, counts,
                                          loss_acc, ticket, out);
}

// Round 9
// 138.226 us; speedup vs baseline: 1.1016x; 1.1016x over previous
//
#include <hip/hip_runtime.h>
#include <math.h>

// Problem constants (match reference)
constexpr int   B       = 2048;
constexpr int   P       = 4;
constexpr int   D       = 256;       // K of the GEMM
constexpr int   NNEG    = 32768;
constexpr int   NTILES  = NNEG / 64; // per-row exp2-sum partials (64-col patches)
constexpr float TEMP    = 0.05f;
constexpr float ALPHA   = 0.1f;
constexpr float EPS     = 1e-12f;
constexpr float INV_T   = 1.0f / TEMP;
// A-side rows are pre-scaled by (1/T)*log2(e) so the MFMA accumulator is
// directly q = sim/T * log2(e), and exp(sim/T) = exp2(q).  |q| <= ~30 so no
// max-tracking is needed (exp2 stays in fp32 range).
constexpr float SCALE_Q = 28.853900817779268f;

typedef __bf16 bf16x8 __attribute__((ext_vector_type(8)));
typedef float  f32x4  __attribute__((ext_vector_type(4)));

// fp32 -> bf16 (RNE), bit-level
__device__ inline unsigned short f2bf(float f) {
  unsigned int u = __float_as_uint(f);
  u = (u + 0x7fffu + ((u >> 16) & 1u)) >> 16;
  return (unsigned short)u;
}

// ---------------------------------------------------------------------------
// FRAGMENT-MAJOR layout: element (row, k) of a [R x 256] bf16 matrix lives at
//   p*4096 + c*512 + q*128 + r*8 + j        (ushort index)
// where p=row>>4, r=row&15, c=k>>5, q=(k>>3)&3, j=k&7.
// A (panel p, chunk c) fragment is 1024 contiguous bytes; MFMA lane l=r+16q
// reads its 16 B at byte offset l*16 -> one perfectly-coalesced
// global_load_dwordx4 per fragment, and global_load_lds staging of a fragment
// is exactly lane-contiguous (dest = base + lane*16).
// k is identically permuted for A and B, so the dot product is unchanged.
// ---------------------------------------------------------------------------

// ---------------------------------------------------------------------------
// Kernel 1 (fused prep): one wave per work row.
//   rows [0, B)         : normalize anchor, scale SCALE_Q, cast bf16 -> frag-major
//   rows [B, B+NNEG)    : normalize negative, cast bf16 -> frag-major
//   rows [B+NNEG,+B*P)  : pos_sim pair dot (exact fp32)
// ---------------------------------------------------------------------------
__global__ void prep_kernel(const float* __restrict__ a,
                            const float* __restrict__ pzx,
                            const float* __restrict__ n,
                            unsigned short* __restrict__ a_bf,
                            unsigned short* __restrict__ n_bf,
                            float* __restrict__ pos_sim,
                            float* __restrict__ loss_acc,
                            unsigned int* __restrict__ ticket) {
  if (blockIdx.x == 0 && threadIdx.x == 0) { *loss_acc = 0.0f; *ticket = 0u; }
  int w    = (blockIdx.x * blockDim.x + threadIdx.x) >> 6;
  int lane = threadIdx.x & 63;
  if (w < B + NNEG) {
    const float* src; unsigned short* dstm; int row; float post;
    if (w < B) { src = a + (size_t)w * D;       dstm = a_bf; row = w;     post = SCALE_Q; }
    else       { src = n + (size_t)(w - B) * D; dstm = n_bf; row = w - B; post = 1.0f; }
    float4 v = ((const float4*)src)[lane];
    float ss = v.x * v.x + v.y * v.y + v.z * v.z + v.w * v.w;
#pragma unroll
    for (int off = 32; off > 0; off >>= 1) ss += __shfl_xor(ss, off, 64);
    float inv = post / fmaxf(sqrtf(ss), EPS);
    ushort4 o;
    o.x = f2bf(v.x * inv); o.y = f2bf(v.y * inv);
    o.z = f2bf(v.z * inv); o.w = f2bf(v.w * inv);
    const int p = row >> 4, r = row & 15;
    const int c = lane >> 3, q = (lane >> 1) & 3, j0 = (lane & 1) * 4;
    *(ushort4*)(dstm + (size_t)p * 4096 + c * 512 + q * 128 + r * 8 + j0) = o;
  } else {
    int pw = w - (B + NNEG);           // 0..B*P-1
    if (pw >= B * P) return;
    int b = pw >> 2;                   // P == 4
    float4 av = ((const float4*)(a + (size_t)b * D))[lane];
    float4 pv = ((const float4*)(pzx + (size_t)pw * D))[lane];
    float d  = av.x * pv.x + av.y * pv.y + av.z * pv.z + av.w * pv.w;
    float sa = av.x * av.x + av.y * av.y + av.z * av.z + av.w * av.w;
    float sp = pv.x * pv.x + pv.y * pv.y + pv.z * pv.z + pv.w * pv.w;
#pragma unroll
    for (int off = 32; off > 0; off >>= 1) {
      d  += __shfl_xor(d, off, 64);
      sa += __shfl_xor(sa, off, 64);
      sp += __shfl_xor(sp, off, 64);
    }
    if (lane == 0) {
      float inva = 1.0f / fmaxf(sqrtf(sa), EPS);
      float invp = 1.0f / fmaxf(sqrtf(sp), EPS);
      pos_sim[pw] = d * inva * invp * INV_T;
    }
  }
}

// ---------------------------------------------------------------------------
// Kernel 2: bf16 MFMA GEMM fused with exp2-sum partials.
//
// Block = 64 x 256 output tile, 4 waves; wave w owns the 64x64 col-patch
// [n0 + w*64, +64).  The block's full-K A-tile (64 rows x 256 k = 32 frags =
// 32 KB) is staged into LDS ONCE via global_load_lds (lane-contiguous in
// frag-major), followed by the kernel's ONLY barrier — zero barriers in the
// K-loop.  B fragments come depth-1 ping-pong direct from frag-major global
// (round-7 proven; named arrays under full unroll = SSA, no spill).
//
// Why 32 KB (not round-8's 64 KB): LDS 32 KB + ~112 VGPR fits 4 blocks/CU
// (occupancy ~50% vs R8's 20%), and per-wave global stream halves to 32 KB
// (B only) — 4 waves/SIMD x 77 cyc/chunk of MFMA covers the ~200 cyc L2
// latency that capped R3/R7/R8 at ~25% MfmaUtil.
//
// XCD swizzle: id&7 -> xcd owns a 16-nblk strip (4096 cols = 2 MB of N) +
// all of A (1 MB) < 4 MB per-XCD L2.
//
// Epilogue: acc holds q = sim/T*log2e (A pre-scaled); per row, sum exp2(q)
// over the wave's 64 cols via 16-lane shuffle reduce -> part_s.
// ---------------------------------------------------------------------------
constexpr int BM = 64, BN = 256;

__global__ __launch_bounds__(256, 4) void negsim_mfma_kernel(
    const unsigned short* __restrict__ Af,   // frag-major [B][256]
    const unsigned short* __restrict__ Nf,   // frag-major [NNEG][256]
    float* __restrict__ part_s) {            // [B][NTILES]
  // 32 fragments x 512 ushorts = 32 KB; frag (panel p, chunk c) at (c*4+p)*512
  __shared__ __align__(16) unsigned short As[32 * 512];

  const int tid  = threadIdx.x;
  const int wave = tid >> 6;   // 0..3 = N-direction patch
  const int lane = tid & 63;

  // XCD-aware decode of flat block id (4096 blocks)
  const int id   = blockIdx.x;
  const int xcd  = id & 7;
  const int j    = id >> 3;              // 0..511
  const int nblk = xcd * 16 + (j & 15);  // 0..127
  const int mblk = j >> 4;               // 0..31
  const int m0   = mblk * BM;
  const int n0   = nblk * BN;

  // ---- stage A-tile (32 frags) once: wave stages frags [wave*8, +8) ----
#pragma unroll
  for (int t = 0; t < 8; t++) {
    const int f = wave * 8 + t;        // 0..31
    const int c = f >> 2, p = f & 3;
    __builtin_amdgcn_global_load_lds(
        (const __attribute__((address_space(1))) unsigned int*)
            (Af + (size_t)((m0 >> 4) + p) * 4096 + c * 512 + lane * 8),
        (__attribute__((address_space(3))) unsigned int*)(As + f * 512 + lane * 8),
        16, 0, 0);
  }
  __syncthreads();   // the kernel's only barrier (drains the staging loads)

  // ---- K-loop: A from LDS, B ping-pong direct from global ----
  const unsigned short* Bp = Nf + (size_t)((n0 >> 4) + wave * 4) * 4096 + lane * 8;

  f32x4 acc[4][4] = {};
  bf16x8 b0[4], b1[4];

#pragma unroll
  for (int ni = 0; ni < 4; ni++)
    b0[ni] = *(const bf16x8*)(Bp + (size_t)ni * 4096);

#pragma unroll
  for (int c = 0; c < 8; c += 2) {
    // prefetch chunk c+1 (c even, c+1 <= 7 always exists)
#pragma unroll
    for (int ni = 0; ni < 4; ni++)
      b1[ni] = *(const bf16x8*)(Bp + (size_t)ni * 4096 + (c + 1) * 512);
    {
      bf16x8 af[4];
#pragma unroll
      for (int mi = 0; mi < 4; mi++)
        af[mi] = *(const bf16x8*)&As[(c * 4 + mi) * 512 + lane * 8];
#pragma unroll
      for (int mi = 0; mi < 4; mi++)
#pragma unroll
        for (int ni = 0; ni < 4; ni++)
          acc[mi][ni] = __builtin_amdgcn_mfma_f32_16x16x32_bf16(
              af[mi], b0[ni], acc[mi][ni], 0, 0, 0);
    }
    if (c + 2 < 8) {
#pragma unroll
      for (int ni = 0; ni < 4; ni++)
        b0[ni] = *(const bf16x8*)(Bp + (size_t)ni * 4096 + (c + 2) * 512);
    }
    {
      bf16x8 af[4];
#pragma unroll
      for (int mi = 0; mi < 4; mi++)
        af[mi] = *(const bf16x8*)&As[((c + 1) * 4 + mi) * 512 + lane * 8];
#pragma unroll
      for (int mi = 0; mi < 4; mi++)
#pragma unroll
        for (int ni = 0; ni < 4; ni++)
          acc[mi][ni] = __builtin_amdgcn_mfma_f32_16x16x32_bf16(
              af[mi], b1[ni], acc[mi][ni], 0, 0, 0);
    }
  }

  // Epilogue: C/D layout row = mi*16 + (lane>>4)*4 + rr, col = ni*16+(lane&15).
#pragma unroll
  for (int mi = 0; mi < 4; mi++) {
#pragma unroll
    for (int rr = 0; rr < 4; rr++) {
      float s = __builtin_amdgcn_exp2f(acc[mi][0][rr]) +
                __builtin_amdgcn_exp2f(acc[mi][1][rr]) +
                __builtin_amdgcn_exp2f(acc[mi][2][rr]) +
                __builtin_amdgcn_exp2f(acc[mi][3][rr]);
#pragma unroll
      for (int off = 1; off < 16; off <<= 1) s += __shfl_xor(s, off, 64);
      if ((lane & 15) == 0) {
        int row = m0 + mi * 16 + (lane >> 4) * 4 + rr;
        part_s[(size_t)row * NTILES + (nblk * 4 + wave)] = s;
      }
    }
  }
}

// ---------------------------------------------------------------------------
// Kernel 3: per-anchor loss + final reduce.  128 blocks x 256 threads; each
// 16-lane group handles one anchor (16-way split of the 512-partial sum).
// One atomicAdd per block (128 total) + ticket; last block writes out[0].
// ---------------------------------------------------------------------------
__global__ void loss_kernel(const float* __restrict__ part_s,
                            const float* __restrict__ pos_sim,
                            const int* __restrict__ counts,
                            float* __restrict__ loss_acc,
                            unsigned int* __restrict__ ticket,
                            float* __restrict__ out) {
  const int tid = threadIdx.x;
  const int b   = blockIdx.x * 16 + (tid >> 4);
  const int sub = tid & 15;
  const float* ps = part_s + (size_t)b * NTILES;
  float s = 0.0f;
#pragma unroll
  for (int i = 0; i < NTILES / 16; i++) s += ps[sub + i * 16];
  s += __shfl_xor(s, 1, 64);
  s += __shfl_xor(s, 2, 64);
  s += __shfl_xor(s, 4, 64);
  s += __shfl_xor(s, 8, 64);   // 16-lane group now holds full S

  float acc = 0.0f;
  if (sub == 0) {
    float L = logf(s);  // neg_lse in natural-log units
    float p0 = pos_sim[b * P + 0], p1 = pos_sim[b * P + 1];
    float p2 = pos_sim[b * P + 2], p3 = pos_sim[b * P + 3];
    int cnt = counts[b];
    float pj[P] = {p0, p1, p2, p3};
#pragma unroll
    for (int jj = 0; jj < P; jj++) {
      if (jj < cnt) {
        float hi = fmaxf(pj[jj], L), lo = fminf(pj[jj], L);
        acc += hi + log1pf(__expf(lo - hi)) - pj[jj];
      }
    }
    float mp = fmaxf(fmaxf(p0, p1), fmaxf(p2, p3));
    float e0 = __expf(p0 - mp), e1 = __expf(p1 - mp);
    float e2 = __expf(p2 - mp), e3 = __expf(p3 - mp);
    float se = e0 + e1 + e2 + e3;
    float wps = (e0 * p0 + e1 * p1 + e2 * p2 + e3 * p3) / se;
    if (cnt > 1) {
      float hi = fmaxf(wps, L), lo = fminf(wps, L);
      acc += ALPHA * (hi + log1pf(__expf(lo - hi)) - wps);
    }
  }
  // block reduce (only sub==0 lanes carry nonzero)
#pragma unroll
  for (int off = 32; off > 0; off >>= 1) acc += __shfl_xor(acc, off, 64);
  __shared__ float sa[4];
  int wid = tid >> 6, lane = tid & 63;
  if (lane == 0) sa[wid] = acc;
  __syncthreads();
  if (tid == 0) {
    atomicAdd(loss_acc, sa[0] + sa[1] + sa[2] + sa[3]);
    __threadfence();
    unsigned int t = atomicAdd(ticket, 1u);
    if (t == (unsigned int)gridDim.x - 1u) {
      float total = atomicAdd(loss_acc, 0.0f);  // atomic read-back
      out[0] = total / (float)B;
    }
  }
}

// ---------------------------------------------------------------------------
extern "C" void kernel_launch(void* const* d_in, const int* in_sizes, int n_in,
                              void* d_out, int out_size, void* d_ws,
                              size_t ws_size, hipStream_t stream) {
  const float* anc    = (const float*)d_in[0];
  const float* pos    = (const float*)d_in[1];
  const float* neg    = (const float*)d_in[2];
  const int*   counts = (const int*)d_in[3];
  float* out = (float*)d_out;

  // Workspace layout: ~21.1 MB
  unsigned short* a_bf = (unsigned short*)d_ws;          // B*D      (1 MB)
  unsigned short* n_bf = a_bf + (size_t)B * D;           // NNEG*D   (16 MB)
  float* part_s  = (float*)(n_bf + (size_t)NNEG * D);    // B*NTILES (4 MB)
  float* pos_sim = part_s + (size_t)B * NTILES;          // B*P
  float* loss_acc = pos_sim + B * P;                     // 1
  unsigned int* ticket = (unsigned int*)(loss_acc + 1);  // 1

  // 43008 work-rows (norm-cast B+NNEG, possim B*P), 4 waves/block
  prep_kernel<<<(B + NNEG + B * P) / 4, 256, 0, stream>>>(
      anc, pos, neg, a_bf, n_bf, pos_sim, loss_acc, ticket);

  negsim_mfma_kernel<<<4096, 256, 0, stream>>>(a_bf, n_bf, part_s);

  loss_kernel<<<B / 16, 256, 0, stream>>>(part_s, pos_sim, counts,
                                          loss_acc, ticket, out);
}